// Round 1
// baseline (235.224 us; speedup 1.0000x reference)
//
#include <hip/hip_runtime.h>

#define NI 6144
#define NJ 6144
#define M_ROWS 1024
#define K_COLS 256
#define ROWS_PER_BLOCK 6
#define EMD_BLOCKS (NI / ROWS_PER_BLOCK)   // 1024

// ---------------------------------------------------------------------------
// Kernel 1: partial sums of  sum_ij x_ij * (|yi0-yj0| + |yi1-yj1|)
// (the /R = *1.25 factor is applied once in the final reduction)
// ---------------------------------------------------------------------------
__global__ __launch_bounds__(256) void emd_partial_kernel(
    const float* __restrict__ y_i, const float* __restrict__ y_j,
    const float* __restrict__ x, float* __restrict__ partial) {
  // Stage all of y_j in LDS: 6144 (eta,phi) pairs = 48 KB, as float4 (2 pairs each)
  __shared__ float4 yjs[NJ / 2];
  const float4* yj4 = (const float4*)y_j;
  for (int t = threadIdx.x; t < NJ / 2; t += 256) yjs[t] = yj4[t];
  __syncthreads();

  float acc = 0.0f;
  const int row0 = blockIdx.x * ROWS_PER_BLOCK;
  for (int r = 0; r < ROWS_PER_BLOCK; ++r) {
    const int i = row0 + r;
    const float yi0 = y_i[2 * i];
    const float yi1 = y_i[2 * i + 1];
    const float4* xrow = (const float4*)(x + (size_t)i * NJ);
#pragma unroll
    for (int t = 0; t < NJ / 4 / 256; ++t) {   // 6 iterations
      const int idx = threadIdx.x + t * 256;   // coalesced float4 of x
      const float4 xv = xrow[idx];
      const float4 ya = yjs[2 * idx];          // y_j pairs for j = 4*idx .. 4*idx+1
      const float4 yb = yjs[2 * idx + 1];      // y_j pairs for j = 4*idx+2 .. 4*idx+3
      acc += xv.x * (fabsf(yi0 - ya.x) + fabsf(yi1 - ya.y));
      acc += xv.y * (fabsf(yi0 - ya.z) + fabsf(yi1 - ya.w));
      acc += xv.z * (fabsf(yi0 - yb.x) + fabsf(yi1 - yb.y));
      acc += xv.w * (fabsf(yi0 - yb.z) + fabsf(yi1 - yb.w));
    }
  }

  // wave (64-lane) shuffle reduce, then cross-wave via LDS
  for (int off = 32; off > 0; off >>= 1) acc += __shfl_down(acc, off, 64);
  __shared__ float wsum[4];
  const int lane = threadIdx.x & 63;
  const int wid = threadIdx.x >> 6;
  if (lane == 0) wsum[wid] = acc;
  __syncthreads();
  if (threadIdx.x == 0)
    partial[blockIdx.x] = wsum[0] + wsum[1] + wsum[2] + wsum[3];
}

// ---------------------------------------------------------------------------
// Kernel 2: blocks 0..1023 — simplex projection of one row of f each.
//           block 1024    — final reduction of the 1024 EMD partials.
// ---------------------------------------------------------------------------
__global__ __launch_bounds__(256) void simplex_and_finish_kernel(
    const float* __restrict__ f, const float* __restrict__ partial,
    float* __restrict__ out) {
  const int tid = threadIdx.x;

  if (blockIdx.x == M_ROWS) {
    // ---- final loss reduction (partials written by previous kernel) ----
    float acc = partial[tid] + partial[tid + 256] + partial[tid + 512] +
                partial[tid + 768];
    for (int off = 32; off > 0; off >>= 1) acc += __shfl_down(acc, off, 64);
    __shared__ float wsum[4];
    const int lane = tid & 63;
    const int wid = tid >> 6;
    if (lane == 0) wsum[wid] = acc;
    __syncthreads();
    if (tid == 0)
      out[0] = (wsum[0] + wsum[1] + wsum[2] + wsum[3]) * 1.25f;  // 1/R = 1/0.8
    return;
  }

  // ---- simplex projection of row blockIdx.x ----
  const int row = blockIdx.x;
  const float fv = f[row * K_COLS + tid];

  __shared__ float s[K_COLS];
  __shared__ float c0[K_COLS];
  __shared__ float c1[K_COLS];
  __shared__ float vbuf[K_COLS];

  s[tid] = fv;
  __syncthreads();

  // Bitonic sort ascending in LDS (256 elements, 256 threads)
  for (int k = 2; k <= K_COLS; k <<= 1) {
    for (int j = k >> 1; j > 0; j >>= 1) {
      const int ixj = tid ^ j;
      if (ixj > tid) {
        const float a = s[tid];
        const float b = s[ixj];
        const bool asc = ((tid & k) == 0);
        if ((a > b) == asc) {  // out of order for this direction -> swap
          s[tid] = b;
          s[ixj] = a;
        }
      }
      __syncthreads();
    }
  }

  // Descending view: u[t] = s[255 - t]; inclusive scan (Hillis-Steele)
  const float u = s[K_COLS - 1 - tid];
  c0[tid] = u;
  __syncthreads();
  float* src = c0;
  float* dst = c1;
  for (int off = 1; off < K_COLS; off <<= 1) {
    float v = src[tid];
    if (tid >= off) v += src[tid - off];
    dst[tid] = v;
    __syncthreads();
    float* tmp = src; src = dst; dst = tmp;
  }
  const float cs = src[tid];                       // cumsum of descending u
  const float vt = (cs - 1.0f) / (float)(tid + 1); // v_k
  vbuf[tid] = vt;
  const int cnt = __syncthreads_count(u > vt);     // rho + 1 (barrier included)
  const float w = vbuf[cnt - 1];

  out[1 + row * K_COLS + tid] = fmaxf(fv - w, 0.0f);
}

// ---------------------------------------------------------------------------
extern "C" void kernel_launch(void* const* d_in, const int* in_sizes, int n_in,
                              void* d_out, int out_size, void* d_ws,
                              size_t ws_size, hipStream_t stream) {
  const float* y_i = (const float*)d_in[0];
  const float* y_j = (const float*)d_in[1];
  const float* x   = (const float*)d_in[2];
  const float* f   = (const float*)d_in[3];
  float* out = (float*)d_out;
  float* partial = (float*)d_ws;  // 1024 floats

  emd_partial_kernel<<<EMD_BLOCKS, 256, 0, stream>>>(y_i, y_j, x, partial);
  simplex_and_finish_kernel<<<M_ROWS + 1, 256, 0, stream>>>(f, partial, out);
}

// Round 2
// 228.347 us; speedup vs baseline: 1.0301x; 1.0301x over previous
//
#include <hip/hip_runtime.h>

#define NI 6144
#define NJ 6144
#define M_ROWS 1024
#define K_COLS 256
#define ROWS_PER_BLOCK 8
#define EMD_BLOCKS (NI / ROWS_PER_BLOCK)   // 768 = exactly 3 blocks/CU on 256 CUs

// ---------------------------------------------------------------------------
// Kernel 1: partial sums of  sum_ij x_ij * (|yi0-yj0| + |yi1-yj1|)
// (the /R = *1.25 factor is applied once in the final reduction)
// ---------------------------------------------------------------------------
__global__ __launch_bounds__(256) void emd_partial_kernel(
    const float* __restrict__ y_i, const float* __restrict__ y_j,
    const float* __restrict__ x, float* __restrict__ partial) {
  // De-interleaved y_j in LDS: yj0[j], yj1[j] as float4 groups of 4 js.
  // Unit-stride ds_read_b128 (2-way bank aliasing = free).
  __shared__ float4 yj0v[NJ / 4];   // 24 KB
  __shared__ float4 yj1v[NJ / 4];   // 24 KB
  {
    const float4* yj4 = (const float4*)y_j;   // (y0,y1,y0,y1) = 2 js
    float* s0 = (float*)yj0v;
    float* s1 = (float*)yj1v;
    for (int t = threadIdx.x; t < NJ / 2; t += 256) {
      const float4 v = yj4[t];
      s0[2 * t]     = v.x;  s1[2 * t]     = v.y;
      s0[2 * t + 1] = v.z;  s1[2 * t + 1] = v.w;
    }
  }
  __syncthreads();

  const int row0 = blockIdx.x * ROWS_PER_BLOCK;
  float yi0[ROWS_PER_BLOCK], yi1[ROWS_PER_BLOCK];
#pragma unroll
  for (int r = 0; r < ROWS_PER_BLOCK; ++r) {
    yi0[r] = y_i[2 * (row0 + r)];
    yi1[r] = y_i[2 * (row0 + r) + 1];
  }

  float acc = 0.0f;
#pragma unroll
  for (int t = 0; t < NJ / 4 / 256; ++t) {       // 6 iterations
    const int idx = threadIdx.x + t * 256;       // float4 group of 4 js
    const float4 ya = yj0v[idx];                 // shared across all 8 rows
    const float4 yb = yj1v[idx];
#pragma unroll
    for (int r = 0; r < ROWS_PER_BLOCK; ++r) {
      const float4 xv =
          ((const float4*)(x + (size_t)(row0 + r) * NJ))[idx];  // coalesced
      acc += xv.x * (fabsf(yi0[r] - ya.x) + fabsf(yi1[r] - yb.x));
      acc += xv.y * (fabsf(yi0[r] - ya.y) + fabsf(yi1[r] - yb.y));
      acc += xv.z * (fabsf(yi0[r] - ya.z) + fabsf(yi1[r] - yb.z));
      acc += xv.w * (fabsf(yi0[r] - ya.w) + fabsf(yi1[r] - yb.w));
    }
  }

  // wave (64-lane) shuffle reduce, then cross-wave via LDS
  for (int off = 32; off > 0; off >>= 1) acc += __shfl_down(acc, off, 64);
  __shared__ float wsum[4];
  const int lane = threadIdx.x & 63;
  const int wid = threadIdx.x >> 6;
  if (lane == 0) wsum[wid] = acc;
  __syncthreads();
  if (threadIdx.x == 0)
    partial[blockIdx.x] = wsum[0] + wsum[1] + wsum[2] + wsum[3];
}

// ---------------------------------------------------------------------------
// Kernel 2: blocks 0..1023 — simplex projection of one row of f each
//           (register bitonic sort: shfl_xor for j<64, LDS only for j>=64).
//           block 1024    — final reduction of the 768 EMD partials.
// ---------------------------------------------------------------------------
__global__ __launch_bounds__(256) void simplex_and_finish_kernel(
    const float* __restrict__ f, const float* __restrict__ partial,
    float* __restrict__ out) {
  const int tid = threadIdx.x;
  const int lane = tid & 63;
  const int wid = tid >> 6;

  __shared__ float s[K_COLS];
  __shared__ float wpre[4];

  if (blockIdx.x == M_ROWS) {
    // ---- final loss reduction (768 partials from previous kernel) ----
    float acc = partial[tid] + partial[tid + 256] + partial[tid + 512];
    for (int off = 32; off > 0; off >>= 1) acc += __shfl_down(acc, off, 64);
    if (lane == 0) wpre[wid] = acc;
    __syncthreads();
    if (tid == 0)
      out[0] = (wpre[0] + wpre[1] + wpre[2] + wpre[3]) * 1.25f;  // 1/R
    return;
  }

  // ---- simplex projection of row blockIdx.x ----
  const int row = blockIdx.x;
  const float fv = f[row * K_COLS + tid];

  // Bitonic sort DESCENDING over 256 values held one-per-thread in x.
  // (tid & k)==0 -> descending sub-block. Lower partner keeps max when
  // direction is descending.
  float x = fv;
#pragma unroll
  for (int k = 2; k <= 64; k <<= 1) {
#pragma unroll
    for (int j = k >> 1; j > 0; j >>= 1) {       // all j < 64: in-wave
      const float pv = __shfl_xor(x, j, 64);
      const bool up = ((tid & k) == 0);
      const bool lower = ((tid & j) == 0);
      x = (up == lower) ? fmaxf(x, pv) : fminf(x, pv);
    }
  }
  // k = 128: j=64 via LDS, then j<64 via shfl
  {
    s[tid] = x; __syncthreads();
    const float pv = s[tid ^ 64]; __syncthreads();
    const bool up = ((tid & 128) == 0);
    x = (up == ((tid & 64) == 0)) ? fmaxf(x, pv) : fminf(x, pv);
#pragma unroll
    for (int j = 32; j > 0; j >>= 1) {
      const float pv2 = __shfl_xor(x, j, 64);
      x = (up == ((tid & j) == 0)) ? fmaxf(x, pv2) : fminf(x, pv2);
    }
  }
  // k = 256 ((tid&256)==0 always: final full descending merge)
  {
    s[tid] = x; __syncthreads();
    float pv = s[tid ^ 128]; __syncthreads();
    x = ((tid & 128) == 0) ? fmaxf(x, pv) : fminf(x, pv);
    s[tid] = x; __syncthreads();
    pv = s[tid ^ 64]; __syncthreads();
    x = ((tid & 64) == 0) ? fmaxf(x, pv) : fminf(x, pv);
#pragma unroll
    for (int j = 32; j > 0; j >>= 1) {
      const float pv2 = __shfl_xor(x, j, 64);
      x = ((tid & j) == 0) ? fmaxf(x, pv2) : fminf(x, pv2);
    }
  }

  const float u = x;  // u[tid] = tid-th largest

  // Inclusive prefix sum of u across 256 threads: shfl_up within wave,
  // then cross-wave offsets via LDS.
  float cs = u;
#pragma unroll
  for (int off = 1; off < 64; off <<= 1) {
    const float t = __shfl_up(cs, off, 64);
    if (lane >= off) cs += t;
  }
  if (lane == 63) wpre[wid] = cs;
  __syncthreads();
  float base = 0.0f;
#pragma unroll
  for (int w = 0; w < 4; ++w)
    if (w < wid) base += wpre[w];
  cs += base;

  const float vt = (cs - 1.0f) / (float)(tid + 1);
  s[tid] = vt;                                   // reuse s as v-buffer
  const int cnt = __syncthreads_count(u > vt);   // rho + 1 (is a barrier)
  const float w = s[cnt - 1];

  out[1 + row * K_COLS + tid] = fmaxf(fv - w, 0.0f);
}

// ---------------------------------------------------------------------------
extern "C" void kernel_launch(void* const* d_in, const int* in_sizes, int n_in,
                              void* d_out, int out_size, void* d_ws,
                              size_t ws_size, hipStream_t stream) {
  const float* y_i = (const float*)d_in[0];
  const float* y_j = (const float*)d_in[1];
  const float* x   = (const float*)d_in[2];
  const float* f   = (const float*)d_in[3];
  float* out = (float*)d_out;
  float* partial = (float*)d_ws;  // 768 floats

  emd_partial_kernel<<<EMD_BLOCKS, 256, 0, stream>>>(y_i, y_j, x, partial);
  simplex_and_finish_kernel<<<M_ROWS + 1, 256, 0, stream>>>(f, partial, out);
}